// Round 10
// baseline (282.529 us; speedup 1.0000x reference)
//
#include <hip/hip_runtime.h>
#include <stdint.h>

#define NEG_SLOPE 0.2f
#define SEPS 1e-16f

typedef short bf16x8 __attribute__((ext_vector_type(8)));
typedef float f32x4 __attribute__((ext_vector_type(4)));

static __device__ __forceinline__ float bf2f(ushort u) {
  union { uint32_t i; float f; } v; v.i = ((uint32_t)u) << 16; return v.f;
}
static __device__ __forceinline__ ushort f2bf(float f) {
  uint32_t b = __float_as_uint(f);
  b += 0x7FFFu + ((b >> 16) & 1u);      // RNE
  return (ushort)(b >> 16);
}
static __device__ __forceinline__ float blo(uint32_t u) { return __uint_as_float(u << 16); }
static __device__ __forceinline__ float bhi(uint32_t u) { return __uint_as_float(u & 0xFFFF0000u); }
static __device__ __forceinline__ float ldf(const void* p, size_t i, int mode) {
  return mode ? ((const float*)p)[i] : bf2f(((const ushort*)p)[i]);
}

// ---------------- fills ----------------
__global__ void fill_out(float* __restrict__ out, int n, float v) {
  int i = blockIdx.x * 256 + threadIdx.x;
  if (i < n) out[i] = v;
}

// ------- prologue: detectors (12 blocks) + deg zero-fill ------------------
struct DetPtrs {
  const uint32_t* p[11];
  int n[11];
  const uint32_t* idx;
  int idxn;
};
__global__ void prologue(DetPtrs dp, int* __restrict__ modes,
                         int* __restrict__ deg, int N) {
  int b = blockIdx.x;
  if (b >= 12) {
    int i = (b - 12) * 256 + threadIdx.x;
    if (i < N) deg[i] = 0;
    return;
  }
  __shared__ int sL, sH;
  if (threadIdx.x == 0) { sL = 0; sH = 0; }
  __syncthreads();
  if (b < 11) {
    const uint32_t* w = dp.p[b];
    int elems = dp.n[b];
    int nprobe = min(2048, elems / 2);
    int cL = 0, cH = 0;
    for (int i = threadIdx.x; i < nprobe; i += 256) {
      uint32_t v = w[i];
      uint32_t eL = (v >> 7) & 0xFFu;
      uint32_t eH = (v >> 23) & 0xFFu;
      if (eL >= 90u && eL <= 128u) cL++;
      if (eH >= 90u && eH <= 128u) cH++;
    }
    atomicAdd(&sL, cL); atomicAdd(&sH, cH);
    __syncthreads();
    if (threadIdx.x == 0) {
      int m;
      if (sL * 4 >= nprobe * 3) m = 0;
      else if (sH * 4 >= nprobe) m = 1;
      else m = 0;
      modes[b] = m;
    }
  } else {
    const uint32_t* w = dp.idx;
    int nprobe = min(4096, dp.idxn);
    int c = 0;
    for (int i = threadIdx.x; i < nprobe; i += 256)
      if ((i & 1) && w[i] == 0u) c++;
    atomicAdd(&sL, c);
    __syncthreads();
    if (threadIdx.x == 0) modes[11] = (sL * 4 >= (nprobe / 2) * 3) ? 1 : 0;
  }
}

// ------- merged canon: deg count + transposed bf16 weights + small tensors
struct WTArgs {
  const void* w1; const void* wmu; const void* wlv;
  ushort* wt1; ushort* wall;
};
struct SmallCan { const void* src[6]; float* dst[6]; int n[6]; int mi[6]; };
struct CanArgs {
  const void* ei;
  int* deg;
  int E; int N; int EB1; int WB;
  WTArgs wt;
  SmallCan sc;
};
__global__ void canon_all(CanArgs a, const int* __restrict__ modes) {
  int b = blockIdx.x;
  if (b < a.EB1) {
    int i = b * 256 + threadIdx.x;
    if (i >= a.E) return;
    int d;
    if (modes[11]) d = (int)((const long long*)a.ei)[a.E + i];
    else           d = ((const int*)a.ei)[a.E + i];
    d = min(max(d, 0), a.N - 1);
    atomicAdd(&a.deg[d], 1);
  } else if (b < a.EB1 + a.WB) {
    int i = (b - a.EB1) * 256 + threadIdx.x;
    const int NW1 = 256 * 512;
    if (i < NW1) {
      int n = i >> 9, k = i & 511;
      float v = ldf(a.wt.w1, (size_t)k * 256 + n, modes[2]);
      if (!isfinite(v)) v = 0.f;
      a.wt.wt1[i] = f2bf(v);
    } else {
      int j = i - NW1;
      if (j >= 256 * 256) return;
      int n = j >> 8, k = j & 255;
      float v;
      if (n < 128) v = ldf(a.wt.wmu, (size_t)k * 128 + n, modes[5]);
      else         v = ldf(a.wt.wlv, (size_t)k * 128 + (n - 128), modes[8]);
      if (!isfinite(v)) v = 0.f;
      a.wt.wall[j] = f2bf(v);
    }
  } else {
    int sb = b - a.EB1 - a.WB;
    int m = modes[a.sc.mi[sb]];
    const void* s = a.sc.src[sb];
    float* d = a.sc.dst[sb];
    for (int i = threadIdx.x; i < a.sc.n[sb]; i += 256) {
      float v = ldf(s, i, m);
      if (!isfinite(v)) v = 0.f;
      d[i] = v;
    }
  }
}

// ---------------- CSR scan ----------------
__global__ __launch_bounds__(1024) void scan_deg(const int* __restrict__ deg,
                                                 int* __restrict__ row_ptr,
                                                 int* __restrict__ row_cur, int N) {
  __shared__ int part[1024];
  int t = threadIdx.x;
  int chunk = (N + 1023) / 1024;
  int lo = t * chunk, hi = min(lo + chunk, N);
  int s = 0;
  for (int i = lo; i < hi; ++i) s += deg[i];
  part[t] = s;
  __syncthreads();
  for (int off = 1; off < 1024; off <<= 1) {
    int v = (t >= off) ? part[t - off] : 0;
    __syncthreads();
    part[t] += v;
    __syncthreads();
  }
  int base = (t == 0) ? 0 : part[t - 1];
  for (int i = lo; i < hi; ++i) {
    row_ptr[i] = base; row_cur[i] = base;
    base += deg[i];
  }
  if (t == 1023) row_ptr[N] = part[1023];
}

// ------- MFMA GEMM 64x256 + fused attention dots (+ optional scatter section)
// Blocks [0,SB): CSR scatter — decodes raw edge index/weight directly (mode
//   via modeA[11]/modeA[1]); ONE int2 {src, w} write per edge (half the
//   random write lines vs two arrays).
// Blocks [SB,..): out_bf16[M][256] = A[M][KTOT] @ WT^T.  WT bf16 [256][KTOT].
// 4 waves 2x2: per wave 32 rows x 128 cols (2x8 frags of 16x16), BK=32.
template <int KTOT, int DMODE>
__global__ __launch_bounds__(256) void gemm_mfma_sc(
    const void* __restrict__ A, const ushort* __restrict__ WT,
    ushort* __restrict__ out, int M,
    const int* __restrict__ modeA, const float* __restrict__ attv,
    float* __restrict__ dotd, float* __restrict__ dotsrc,
    int SB, const void* __restrict__ ei, const void* __restrict__ ew,
    int* __restrict__ row_cur, int2* __restrict__ csr, int E) {
  __shared__ ushort As[64][40];    // 80B pitch: 2-way bank alias (free)
  __shared__ ushort Bs[256][40];

  if ((int)blockIdx.x < SB) {      // scatter section
    int e = blockIdx.x * 256 + threadIdx.x;
    if (e < E) {
      int s, d;
      if (modeA[11]) {
        s = (int)((const long long*)ei)[e];
        d = (int)((const long long*)ei)[E + e];
      } else {
        s = ((const int*)ei)[e];
        d = ((const int*)ei)[E + e];
      }
      s = min(max(s, 0), M - 1);
      d = min(max(d, 0), M - 1);
      float w = ldf(ew, e, modeA[1]);
      if (!isfinite(w)) w = 0.f;
      int p = atomicAdd(&row_cur[d], 1);
      csr[p] = make_int2(s, __float_as_int(w));
    }
    return;
  }

  int t = threadIdx.x;
  int m0 = (blockIdx.x - SB) * 64;
  int wid = t >> 6, l = t & 63;
  int wr = wid >> 1, wc = wid & 1;
  int mode = modeA ? *modeA : 0;

  int arow = t >> 2;
  int akoff = (t & 3) * 8;
  int srow = min(m0 + arow, M - 1);

  f32x4 acc[2][8];
#pragma unroll
  for (int i = 0; i < 2; ++i)
#pragma unroll
    for (int j = 0; j < 8; ++j) acc[i][j] = (f32x4){0.f, 0.f, 0.f, 0.f};

  int cl = l & 15;
  int ksl = (l >> 4) * 8;

  for (int k0 = 0; k0 < KTOT; k0 += 32) {
    if (mode) {
      const float* Af = (const float*)A + (size_t)srow * KTOT + k0 + akoff;
      float4 v0 = *(const float4*)Af;
      float4 v1 = *(const float4*)(Af + 4);
      uint4 pk;
      pk.x = (uint32_t)f2bf(v0.x) | ((uint32_t)f2bf(v0.y) << 16);
      pk.y = (uint32_t)f2bf(v0.z) | ((uint32_t)f2bf(v0.w) << 16);
      pk.z = (uint32_t)f2bf(v1.x) | ((uint32_t)f2bf(v1.y) << 16);
      pk.w = (uint32_t)f2bf(v1.z) | ((uint32_t)f2bf(v1.w) << 16);
      *(uint4*)&As[arow][akoff] = pk;
    } else {
      *(uint4*)&As[arow][akoff] =
          *(const uint4*)((const ushort*)A + (size_t)srow * KTOT + k0 + akoff);
    }
#pragma unroll
    for (int i = 0; i < 4; ++i) {
      int f = t + i * 256;
      int row = f >> 2, koff = (f & 3) * 8;
      *(uint4*)&Bs[row][koff] = *(const uint4*)(WT + (size_t)row * KTOT + k0 + koff);
    }
    __syncthreads();

    bf16x8 af[2], bfr[8];
#pragma unroll
    for (int i = 0; i < 2; ++i)
      af[i] = *(const bf16x8*)&As[wr * 32 + i * 16 + cl][ksl];
#pragma unroll
    for (int j = 0; j < 8; ++j)
      bfr[j] = *(const bf16x8*)&Bs[wc * 128 + j * 16 + cl][ksl];
#pragma unroll
    for (int i = 0; i < 2; ++i)
#pragma unroll
      for (int j = 0; j < 8; ++j)
        acc[i][j] = __builtin_amdgcn_mfma_f32_16x16x32_bf16(af[i], bfr[j], acc[i][j], 0, 0, 0);
    __syncthreads();
  }

  int rb = (l >> 4) * 4;

  // ---- fused attention-dot epilogue (plain stores; block covers all cols) ----
  if (DMODE == 1) {
    float wdv[8], wsv[8];
#pragma unroll
    for (int j = 0; j < 8; ++j) {
      int h = wc * 2 + (j >> 2);
      int c = (j & 3) * 16 + cl;
      wdv[j] = attv[h * 128 + c];
      wsv[j] = attv[h * 128 + 64 + c];
    }
#pragma unroll
    for (int i = 0; i < 2; ++i)
#pragma unroll
      for (int r = 0; r < 4; ++r) {
        float pd0 = acc[i][0][r] * wdv[0] + acc[i][1][r] * wdv[1]
                  + acc[i][2][r] * wdv[2] + acc[i][3][r] * wdv[3];
        float ps0 = acc[i][0][r] * wsv[0] + acc[i][1][r] * wsv[1]
                  + acc[i][2][r] * wsv[2] + acc[i][3][r] * wsv[3];
        float pd1 = acc[i][4][r] * wdv[4] + acc[i][5][r] * wdv[5]
                  + acc[i][6][r] * wdv[6] + acc[i][7][r] * wdv[7];
        float ps1 = acc[i][4][r] * wsv[4] + acc[i][5][r] * wsv[5]
                  + acc[i][6][r] * wsv[6] + acc[i][7][r] * wsv[7];
#pragma unroll
        for (int d = 1; d < 16; d <<= 1) {
          pd0 += __shfl_xor(pd0, d); ps0 += __shfl_xor(ps0, d);
          pd1 += __shfl_xor(pd1, d); ps1 += __shfl_xor(ps1, d);
        }
        if (cl == 0) {
          int m = m0 + wr * 32 + i * 16 + rb + r;
          if (m < M) {
            dotd[m * 4 + wc * 2] = pd0;
            dotsrc[m * 4 + wc * 2] = ps0;
            dotd[m * 4 + wc * 2 + 1] = pd1;
            dotsrc[m * 4 + wc * 2 + 1] = ps1;
          }
        }
      }
  } else if (DMODE == 2) {
    float wdv[8], wsv[8];
#pragma unroll
    for (int j = 0; j < 8; ++j) {
      int c = j * 16 + cl;
      wdv[j] = attv[wc * 256 + c];
      wsv[j] = attv[wc * 256 + 128 + c];
    }
#pragma unroll
    for (int i = 0; i < 2; ++i)
#pragma unroll
      for (int r = 0; r < 4; ++r) {
        float pd = 0.f, ps = 0.f;
#pragma unroll
        for (int j = 0; j < 8; ++j) {
          pd += acc[i][j][r] * wdv[j];
          ps += acc[i][j][r] * wsv[j];
        }
#pragma unroll
        for (int d = 1; d < 16; d <<= 1) {
          pd += __shfl_xor(pd, d); ps += __shfl_xor(ps, d);
        }
        if (cl == 0) {
          int m = m0 + wr * 32 + i * 16 + rb + r;
          if (m < M) {
            dotd[m * 4 + wc * 2] = pd;
            dotd[m * 4 + wc * 2 + 1] = ps;
          }
        }
      }
  }

#pragma unroll
  for (int i = 0; i < 2; ++i)
#pragma unroll
    for (int j = 0; j < 8; ++j)
#pragma unroll
      for (int r = 0; r < 4; ++r) {
        int m = m0 + wr * 32 + i * 16 + rb + r;
        if (m < M)
          out[(size_t)m * 256 + wc * 128 + j * 16 + cl] = f2bf(acc[i][j][r]);
      }
}

// -------- layer-1 fused: ONE WAVE PER NODE, online softmax, bf16 out ------
// Gather unrolled x2: 4 uint4 loads in flight per wave (2 subgroups x 2).
__global__ __launch_bounds__(256) void fused_agg1_wave(
    const int* __restrict__ row_ptr, const int2* __restrict__ csr,
    const float* __restrict__ ad, const float* __restrict__ as_,
    const ushort* __restrict__ xp, const float* __restrict__ b1,
    ushort* __restrict__ hout, int N) {
  int n = blockIdx.x * 4 + (threadIdx.x >> 6);
  if (n >= N) return;
  int lane = threadIdx.x & 63;
  int h = lane & 3;
  int es = lane >> 2;
  int sg = lane >> 5, l = lane & 31, hl = l >> 3;

  int lo = row_ptr[n], hi = row_ptr[n + 1];
  float adv = ad[n * 4 + h];

  float m = -1e30f;
  float dsum = 0.f;
  float acc[8];
#pragma unroll
  for (int j = 0; j < 8; ++j) acc[j] = 0.f;

  for (int cb = lo; cb < hi; cb += 16) {
    int cn = min(16, hi - cb);
    float a = -1e30f;
    int sreg = 0;
    float wreg = 0.f;
    if (es < cn) {
      int2 sw = csr[cb + es];
      sreg = sw.x;
      wreg = __int_as_float(sw.y);
      float aa = adv + as_[sreg * 4 + h];
      a = aa >= 0.f ? aa : NEG_SLOPE * aa;
    }
    float cm = a;
    cm = fmaxf(cm, __shfl_xor(cm, 4));
    cm = fmaxf(cm, __shfl_xor(cm, 8));
    cm = fmaxf(cm, __shfl_xor(cm, 16));
    cm = fmaxf(cm, __shfl_xor(cm, 32));
    float mnew = fmaxf(m, cm);
    float scale = expf(m - mnew);       // first chunk: exp(-inf)=0
    m = mnew;
    float ev = (es < cn) ? expf(a - m) : 0.f;
    dsum = dsum * scale + ev;
    float cwreg = ev * wreg;
    float sc = __shfl(scale, hl);       // lane hl: (es=0, h=hl)
#pragma unroll
    for (int j = 0; j < 8; ++j) acc[j] *= sc;
    for (int el2 = 0; el2 < cn; el2 += 4) {
      int ea = el2 + sg, eb = el2 + 2 + sg;
      int eac = min(ea, cn - 1), ebc = min(eb, cn - 1);
      float cwa = __shfl(cwreg, (eac << 2) | hl);
      int sa = __shfl(sreg, eac << 2);
      float cwb = __shfl(cwreg, (ebc << 2) | hl);
      int sb = __shfl(sreg, ebc << 2);
      bool pa = ea < cn, pb = eb < cn;
      uint4 va, vb;
      if (pa) va = *(const uint4*)(xp + (size_t)sa * 256 + l * 8);
      if (pb) vb = *(const uint4*)(xp + (size_t)sb * 256 + l * 8);
      if (pa) {
        acc[0] += cwa * blo(va.x); acc[1] += cwa * bhi(va.x);
        acc[2] += cwa * blo(va.y); acc[3] += cwa * bhi(va.y);
        acc[4] += cwa * blo(va.z); acc[5] += cwa * bhi(va.z);
        acc[6] += cwa * blo(va.w); acc[7] += cwa * bhi(va.w);
      }
      if (pb) {
        acc[0] += cwb * blo(vb.x); acc[1] += cwb * bhi(vb.x);
        acc[2] += cwb * blo(vb.y); acc[3] += cwb * bhi(vb.y);
        acc[4] += cwb * blo(vb.z); acc[5] += cwb * bhi(vb.z);
        acc[6] += cwb * blo(vb.w); acc[7] += cwb * bhi(vb.w);
      }
    }
  }

  dsum += __shfl_xor(dsum, 4);
  dsum += __shfl_xor(dsum, 8);
  dsum += __shfl_xor(dsum, 16);
  dsum += __shfl_xor(dsum, 32);
  float den = __shfl(dsum, hl);

#pragma unroll
  for (int j = 0; j < 8; ++j) acc[j] += __shfl_down(acc[j], 32);

  if (sg == 0) {
    float inv = 1.0f / (den + SEPS);
    uint4 pk;
    uint32_t w[4];
#pragma unroll
    for (int q = 0; q < 4; ++q) {
      float v0 = acc[q * 2] * inv + b1[l * 8 + q * 2];
      float v1 = acc[q * 2 + 1] * inv + b1[l * 8 + q * 2 + 1];
      v0 = v0 > 0.f ? v0 : expm1f(v0);
      v1 = v1 > 0.f ? v1 : expm1f(v1);
      w[q] = (uint32_t)f2bf(v0) | ((uint32_t)f2bf(v1) << 16);
    }
    pk.x = w[0]; pk.y = w[1]; pk.z = w[2]; pk.w = w[3];
    *(uint4*)(hout + (size_t)n * 256 + l * 8) = pk;
  }
}

// -------- layer-2 fused: ONE WAVE PER NODE, online softmax, 16B gathers ---
// Alpha phase: lanes 0-31 mu alphas, lanes 32-63 lv alphas (half = lane>>5).
// Gather: 2 subgroups of 32 lanes; subgroup reads a FULL 512B hp2 row at
//   16B/lane; lane's row-half hh = (l>>4): 0=mu ch, 1=lv ch. cw/scale/den
//   for half hh shuffled from lane hh*32. 2 edges in flight.
__global__ __launch_bounds__(256) void fused_agg2_wave(
    const int* __restrict__ row_ptr, const int2* __restrict__ csr,
    const float* __restrict__ a4, const ushort* __restrict__ hp2,
    const float* __restrict__ bmu, const float* __restrict__ blv,
    float* __restrict__ out, int N) {
  int n = blockIdx.x * 4 + (threadIdx.x >> 6);
  if (n >= N) return;
  int lane = threadIdx.x & 63;
  int e31 = lane & 31;            // edge slot (alpha phase)
  int half = lane >> 5;           // alpha slot: 0=mu, 1=lv
  int sg = lane >> 5;             // gather subgroup
  int l = lane & 31;              // gather lane within subgroup
  int hh = l >> 4;                // row half this lane gathers (0=mu,1=lv)
  int hlane = hh << 5;            // representative lane of half hh

  int lo = row_ptr[n], hi = row_ptr[n + 1];
  float adv = a4[n * 4 + half * 2];

  float m = -1e30f;
  float dsum = 0.f;
  float acc[8];
#pragma unroll
  for (int j = 0; j < 8; ++j) acc[j] = 0.f;

  for (int cb = lo; cb < hi; cb += 32) {
    int cn = min(32, hi - cb);
    float a = -1e30f;
    int sreg = 0;
    float wreg = 0.f;
    if (e31 < cn) {
      int2 sw = csr[cb + e31];
      sreg = sw.x;
      wreg = __int_as_float(sw.y);
      float aa = adv + a4[sreg * 4 + half * 2 + 1];
      a = aa >= 0.f ? aa : NEG_SLOPE * aa;
    }
    // per-half chunk max (masks 1..16 stay within each 32-lane half)
    float cm = a;
    cm = fmaxf(cm, __shfl_xor(cm, 1));
    cm = fmaxf(cm, __shfl_xor(cm, 2));
    cm = fmaxf(cm, __shfl_xor(cm, 4));
    cm = fmaxf(cm, __shfl_xor(cm, 8));
    cm = fmaxf(cm, __shfl_xor(cm, 16));
    float mnew = fmaxf(m, cm);
    float scale = expf(m - mnew);       // first chunk: exp(-inf)=0
    m = mnew;
    float ev = (e31 < cn) ? expf(a - m) : 0.f;
    dsum = dsum * scale + ev;
    float cwreg = ev * wreg;
    float sc = __shfl(scale, hlane);    // my GATHER half's rescale
#pragma unroll
    for (int j = 0; j < 8; ++j) acc[j] *= sc;
    for (int el2 = 0; el2 < cn; el2 += 2) {
      int el = el2 + sg;
      int elc = min(el, cn - 1);
      float cw = __shfl(cwreg, elc | (hh << 5));   // half hh's weight, edge elc
      int s = __shfl(sreg, elc);                   // lanes 0-31 hold src ids
      if (el < cn) {
        uint4 v = *(const uint4*)(hp2 + (size_t)s * 256 + l * 8);
        acc[0] += cw * blo(v.x); acc[1] += cw * bhi(v.x);
        acc[2] += cw * blo(v.y); acc[3] += cw * bhi(v.y);
        acc[4] += cw * blo(v.z); acc[5] += cw * bhi(v.z);
        acc[6] += cw * blo(v.w); acc[7] += cw * bhi(v.w);
      }
    }
  }

  // per-half denom reduce
  dsum += __shfl_xor(dsum, 1);
  dsum += __shfl_xor(dsum, 2);
  dsum += __shfl_xor(dsum, 4);
  dsum += __shfl_xor(dsum, 8);
  dsum += __shfl_xor(dsum, 16);
  float den = __shfl(dsum, hlane);      // my gather half's denominator

  // cross-subgroup accumulate reduce (lane l and l+32 cover same channels)
#pragma unroll
  for (int j = 0; j < 8; ++j) acc[j] += __shfl_down(acc[j], 32);

  if (sg == 0) {
    float inv = 1.0f / (den + SEPS);
    const float* bb = hh ? blv : bmu;
    int c0 = (l & 15) * 8;
    float* op = out + (size_t)hh * N * 128 + (size_t)n * 128 + c0;
#pragma unroll
    for (int j = 0; j < 8; ++j) op[j] = acc[j] * inv + bb[c0 + j];
  }
}

extern "C" void kernel_launch(void* const* d_in, const int* in_sizes, int n_in,
                              void* d_out, int out_size, void* d_ws, size_t ws_size,
                              hipStream_t stream) {
  int OB = (out_size + 255) / 256;
  bool ok = (n_in == 12);
  int HID = 0, IN = 0, N = 0, LAT = 0, E = 0;
  if (ok) {
    HID = in_sizes[5];
    ok = ok && HID == 256;
    IN = HID ? in_sizes[3] / HID : 0;
    ok = ok && IN == 512 && in_sizes[3] == IN * HID;
    N = IN ? in_sizes[0] / IN : 0;
    ok = ok && N > 0 && in_sizes[0] == N * IN && (N % 4) == 0;
    LAT = in_sizes[8];
    ok = ok && LAT == 128;
    E = in_sizes[2];
    ok = ok && E > 0 && in_sizes[1] == 2 * E;
    ok = ok && in_sizes[4] == 2 * HID && in_sizes[6] == HID * LAT &&
         in_sizes[7] == 2 * LAT && in_sizes[9] == HID * LAT &&
         in_sizes[10] == 2 * LAT && in_sizes[11] == LAT &&
         out_size == 2 * N * LAT;
  }
  if (!ok) { fill_out<<<OB, 256, 0, stream>>>((float*)d_out, out_size, 2.0f); return; }

  char* p = (char*)d_ws;
  auto alloc = [&](size_t bytes) -> char* {
    char* r = p;
    p += (bytes + 255) & ~((size_t)255);
    return r;
  };
  ushort* xp_bf = (ushort*)alloc((size_t)N * HID * 2);   // later: hp2 (mu|lv)
  ushort* hreg  = (ushort*)alloc((size_t)N * HID * 2);   // bf16 h (post-ELU)
  ushort* WT1b  = (ushort*)alloc((size_t)HID * IN * 2);  // [256][512] bf16 transposed
  ushort* WallT = (ushort*)alloc((size_t)2 * LAT * HID * 2); // [256][256] bf16 (mu|lv)
  float*  dots  = (float*) alloc((size_t)N * 12 * 4);    // ad1 | as1 | a4
  float*  att1f = (float*) alloc((size_t)2 * HID * 4);
  float*  att2f = (float*) alloc((size_t)4 * LAT * 4);   // attmu(256) | attlv(256)
  float*  b1f   = (float*) alloc((size_t)HID * 4);
  float*  bmuf  = (float*) alloc((size_t)LAT * 4);
  float*  blvf  = (float*) alloc((size_t)LAT * 4);
  int2*   csr   = (int2*)  alloc((size_t)E * 8);         // {src, w} per slot
  int*    row_ptr=(int*)   alloc((size_t)(N + 1) * 4);
  int*    row_cur=(int*)   alloc((size_t)N * 4);
  int*    deg   = (int*)   alloc((size_t)N * 4);
  int*    modes = (int*)   alloc(16 * 4);

  size_t need = (size_t)(p - (char*)d_ws);
  if (need > ws_size) {
    fill_out<<<OB, 256, 0, stream>>>((float*)d_out, out_size, 3.0f);
    return;
  }

  ushort* hp2 = xp_bf;            // gemm2 writes after fused_agg1's last xp read
  float* ad1 = dots;
  float* as1 = dots + (size_t)N * 4;
  float* a4  = dots + (size_t)N * 8;

  // ---- prologue: detection + deg fill (single launch) ----
  const int fidx[11] = {0, 2, 3, 4, 5, 6, 7, 8, 9, 10, 11};
  DetPtrs dp;
  for (int i = 0; i < 11; ++i) {
    dp.p[i] = (const uint32_t*)d_in[fidx[i]];
    dp.n[i] = in_sizes[fidx[i]];
  }
  dp.idx = (const uint32_t*)d_in[1];
  dp.idxn = 2 * E;
  int nbDeg = (N + 255) / 256;
  prologue<<<12 + nbDeg, 256, 0, stream>>>(dp, modes, deg, N);

  // ---- canonicalization (single launch) ----
  int EB1 = (E + 255) / 256;
  int WB = (HID * IN + 2 * LAT * HID + 255) / 256;
  CanArgs ca;
  ca.ei = d_in[1];
  ca.deg = deg;
  ca.E = E; ca.N = N; ca.EB1 = EB1; ca.WB = WB;
  ca.wt.w1 = d_in[3]; ca.wt.wmu = d_in[6]; ca.wt.wlv = d_in[9];
  ca.wt.wt1 = WT1b; ca.wt.wall = WallT;
  ca.sc.src[0] = d_in[4];  ca.sc.dst[0] = att1f;        ca.sc.n[0] = 2 * HID; ca.sc.mi[0] = 3;
  ca.sc.src[1] = d_in[5];  ca.sc.dst[1] = b1f;          ca.sc.n[1] = HID;     ca.sc.mi[1] = 4;
  ca.sc.src[2] = d_in[7];  ca.sc.dst[2] = att2f;        ca.sc.n[2] = 2 * LAT; ca.sc.mi[2] = 6;
  ca.sc.src[3] = d_in[8];  ca.sc.dst[3] = bmuf;         ca.sc.n[3] = LAT;     ca.sc.mi[3] = 7;
  ca.sc.src[4] = d_in[10]; ca.sc.dst[4] = att2f + 256;  ca.sc.n[4] = 2 * LAT; ca.sc.mi[4] = 9;
  ca.sc.src[5] = d_in[11]; ca.sc.dst[5] = blvf;         ca.sc.n[5] = LAT;     ca.sc.mi[5] = 10;
  canon_all<<<EB1 + WB + 6, 256, 0, stream>>>(ca, modes);

  // ---- CSR scan ----
  scan_deg<<<1, 1024, 0, stream>>>(deg, row_ptr, row_cur, N);

  int MB = (N + 63) / 64;

  // ---- layer 1: scatter (blocks 0..EB1) + GEMM (blocks EB1..) in ONE launch
  gemm_mfma_sc<512, 1><<<EB1 + MB, 256, 0, stream>>>(
      d_in[0], WT1b, xp_bf, N, &modes[0], att1f, ad1, as1,
      EB1, d_in[1], d_in[2], row_cur, csr, E);
  fused_agg1_wave<<<(N + 3) / 4, 256, 0, stream>>>(row_ptr, csr,
                                                   ad1, as1, xp_bf, b1f, hreg, N);

  // ---- layer 2 (single GEMM mu|lv, bf16 A + fused node dots) ----
  gemm_mfma_sc<256, 2><<<MB, 256, 0, stream>>>(
      hreg, WallT, hp2, N, nullptr, att2f, a4, nullptr,
      0, nullptr, nullptr, nullptr, nullptr, 0);
  fused_agg2_wave<<<(N + 3) / 4, 256, 0, stream>>>(row_ptr, csr, a4,
                                                   hp2, bmuf, blvf,
                                                   (float*)d_out, N);
}

// Round 11
// 276.243 us; speedup vs baseline: 1.0228x; 1.0228x over previous
//
#include <hip/hip_runtime.h>
#include <stdint.h>

#define NEG_SLOPE 0.2f
#define SEPS 1e-16f

typedef short bf16x8 __attribute__((ext_vector_type(8)));
typedef float f32x4 __attribute__((ext_vector_type(4)));

static __device__ __forceinline__ float bf2f(ushort u) {
  union { uint32_t i; float f; } v; v.i = ((uint32_t)u) << 16; return v.f;
}
static __device__ __forceinline__ ushort f2bf(float f) {
  uint32_t b = __float_as_uint(f);
  b += 0x7FFFu + ((b >> 16) & 1u);      // RNE
  return (ushort)(b >> 16);
}
static __device__ __forceinline__ float blo(uint32_t u) { return __uint_as_float(u << 16); }
static __device__ __forceinline__ float bhi(uint32_t u) { return __uint_as_float(u & 0xFFFF0000u); }
static __device__ __forceinline__ float ldf(const void* p, size_t i, int mode) {
  return mode ? ((const float*)p)[i] : bf2f(((const ushort*)p)[i]);
}

// ---------------- fills ----------------
__global__ void fill_out(float* __restrict__ out, int n, float v) {
  int i = blockIdx.x * 256 + threadIdx.x;
  if (i < n) out[i] = v;
}

// ------- prologue: detectors (12 blocks) + deg zero-fill ------------------
struct DetPtrs {
  const uint32_t* p[11];
  int n[11];
  const uint32_t* idx;
  int idxn;
};
__global__ void prologue(DetPtrs dp, int* __restrict__ modes,
                         int* __restrict__ deg, int N) {
  int b = blockIdx.x;
  if (b >= 12) {
    int i = (b - 12) * 256 + threadIdx.x;
    if (i < N) deg[i] = 0;
    return;
  }
  __shared__ int sL, sH;
  if (threadIdx.x == 0) { sL = 0; sH = 0; }
  __syncthreads();
  if (b < 11) {
    const uint32_t* w = dp.p[b];
    int elems = dp.n[b];
    int nprobe = min(2048, elems / 2);
    int cL = 0, cH = 0;
    for (int i = threadIdx.x; i < nprobe; i += 256) {
      uint32_t v = w[i];
      uint32_t eL = (v >> 7) & 0xFFu;
      uint32_t eH = (v >> 23) & 0xFFu;
      if (eL >= 90u && eL <= 128u) cL++;
      if (eH >= 90u && eH <= 128u) cH++;
    }
    atomicAdd(&sL, cL); atomicAdd(&sH, cH);
    __syncthreads();
    if (threadIdx.x == 0) {
      int m;
      if (sL * 4 >= nprobe * 3) m = 0;
      else if (sH * 4 >= nprobe) m = 1;
      else m = 0;
      modes[b] = m;
    }
  } else {
    const uint32_t* w = dp.idx;
    int nprobe = min(4096, dp.idxn);
    int c = 0;
    for (int i = threadIdx.x; i < nprobe; i += 256)
      if ((i & 1) && w[i] == 0u) c++;
    atomicAdd(&sL, c);
    __syncthreads();
    if (threadIdx.x == 0) modes[11] = (sL * 4 >= (nprobe / 2) * 3) ? 1 : 0;
  }
}

// ------- merged canon: deg count + transposed bf16 weights + small tensors
struct WTArgs {
  const void* w1; const void* wmu; const void* wlv;
  ushort* wt1; ushort* wall;
};
struct SmallCan { const void* src[6]; float* dst[6]; int n[6]; int mi[6]; };
struct CanArgs {
  const void* ei;
  int* deg;
  int E; int N; int EB1; int WB;
  WTArgs wt;
  SmallCan sc;
};
__global__ void canon_all(CanArgs a, const int* __restrict__ modes) {
  int b = blockIdx.x;
  if (b < a.EB1) {
    int i = b * 256 + threadIdx.x;
    if (i >= a.E) return;
    int d;
    if (modes[11]) d = (int)((const long long*)a.ei)[a.E + i];
    else           d = ((const int*)a.ei)[a.E + i];
    d = min(max(d, 0), a.N - 1);
    atomicAdd(&a.deg[d], 1);
  } else if (b < a.EB1 + a.WB) {
    int i = (b - a.EB1) * 256 + threadIdx.x;
    const int NW1 = 256 * 512;
    if (i < NW1) {
      int n = i >> 9, k = i & 511;
      float v = ldf(a.wt.w1, (size_t)k * 256 + n, modes[2]);
      if (!isfinite(v)) v = 0.f;
      a.wt.wt1[i] = f2bf(v);
    } else {
      int j = i - NW1;
      if (j >= 256 * 256) return;
      int n = j >> 8, k = j & 255;
      float v;
      if (n < 128) v = ldf(a.wt.wmu, (size_t)k * 128 + n, modes[5]);
      else         v = ldf(a.wt.wlv, (size_t)k * 128 + (n - 128), modes[8]);
      if (!isfinite(v)) v = 0.f;
      a.wt.wall[j] = f2bf(v);
    }
  } else {
    int sb = b - a.EB1 - a.WB;
    int m = modes[a.sc.mi[sb]];
    const void* s = a.sc.src[sb];
    float* d = a.sc.dst[sb];
    for (int i = threadIdx.x; i < a.sc.n[sb]; i += 256) {
      float v = ldf(s, i, m);
      if (!isfinite(v)) v = 0.f;
      d[i] = v;
    }
  }
}

// ---------------- CSR scan ----------------
__global__ __launch_bounds__(1024) void scan_deg(const int* __restrict__ deg,
                                                 int* __restrict__ row_ptr,
                                                 int* __restrict__ row_cur, int N) {
  __shared__ int part[1024];
  int t = threadIdx.x;
  int chunk = (N + 1023) / 1024;
  int lo = t * chunk, hi = min(lo + chunk, N);
  int s = 0;
  for (int i = lo; i < hi; ++i) s += deg[i];
  part[t] = s;
  __syncthreads();
  for (int off = 1; off < 1024; off <<= 1) {
    int v = (t >= off) ? part[t - off] : 0;
    __syncthreads();
    part[t] += v;
    __syncthreads();
  }
  int base = (t == 0) ? 0 : part[t - 1];
  for (int i = lo; i < hi; ++i) {
    row_ptr[i] = base; row_cur[i] = base;
    base += deg[i];
  }
  if (t == 1023) row_ptr[N] = part[1023];
}

// ------- MFMA GEMM 32x256 + fused attention dots (+ optional scatter section)
// Blocks [0,SB): CSR scatter — decodes raw edge index/weight directly; one
//   int2 {src, w} write per edge.
// Blocks [SB,..): out_bf16[M][256] = A[M][KTOT] @ WT^T.  WT bf16 [256][KTOT].
// 32-row tile doubles grid parallelism vs 64 (R10: 313 blocks -> 14% occ,
// latency-bound at 58us). 4 waves, wave w = cols w*64..w*64+63 (1x4 frags,
// 2 row-frags), BK=32.
template <int KTOT, int DMODE>
__global__ __launch_bounds__(256) void gemm_mfma_sc(
    const void* __restrict__ A, const ushort* __restrict__ WT,
    ushort* __restrict__ out, int M,
    const int* __restrict__ modeA, const float* __restrict__ attv,
    float* __restrict__ dotd, float* __restrict__ dotsrc,
    int SB, const void* __restrict__ ei, const void* __restrict__ ew,
    int* __restrict__ row_cur, int2* __restrict__ csr, int E) {
  __shared__ ushort As[32][40];    // 80B pitch: 2-way bank alias (free)
  __shared__ ushort Bs[256][40];
  __shared__ float red[4][32][2];  // DMODE2 cross-wave dot partials

  if ((int)blockIdx.x < SB) {      // scatter section
    int e = blockIdx.x * 256 + threadIdx.x;
    if (e < E) {
      int s, d;
      if (modeA[11]) {
        s = (int)((const long long*)ei)[e];
        d = (int)((const long long*)ei)[E + e];
      } else {
        s = ((const int*)ei)[e];
        d = ((const int*)ei)[E + e];
      }
      s = min(max(s, 0), M - 1);
      d = min(max(d, 0), M - 1);
      float w = ldf(ew, e, modeA[1]);
      if (!isfinite(w)) w = 0.f;
      int p = atomicAdd(&row_cur[d], 1);
      csr[p] = make_int2(s, __float_as_int(w));
    }
    return;
  }

  int t = threadIdx.x;
  int m0 = (blockIdx.x - SB) * 32;
  int wid = t >> 6, l = t & 63;
  int mode = modeA ? *modeA : 0;

  int arow = t >> 3;               // 0..31
  int akoff = (t & 7) * 4;         // 0,4,...,28
  int srow = min(m0 + arow, M - 1);

  f32x4 acc[2][4];
#pragma unroll
  for (int i = 0; i < 2; ++i)
#pragma unroll
    for (int j = 0; j < 4; ++j) acc[i][j] = (f32x4){0.f, 0.f, 0.f, 0.f};

  int cl = l & 15;
  int ksl = (l >> 4) * 8;

  for (int k0 = 0; k0 < KTOT; k0 += 32) {
    if (mode) {
      const float4 v = *(const float4*)((const float*)A + (size_t)srow * KTOT + k0 + akoff);
      uint2 pk;
      pk.x = (uint32_t)f2bf(v.x) | ((uint32_t)f2bf(v.y) << 16);
      pk.y = (uint32_t)f2bf(v.z) | ((uint32_t)f2bf(v.w) << 16);
      *(uint2*)&As[arow][akoff] = pk;
    } else {
      *(uint2*)&As[arow][akoff] =
          *(const uint2*)((const ushort*)A + (size_t)srow * KTOT + k0 + akoff);
    }
#pragma unroll
    for (int i = 0; i < 4; ++i) {
      int f = t + i * 256;
      int row = f >> 2, koff = (f & 3) * 8;
      *(uint4*)&Bs[row][koff] = *(const uint4*)(WT + (size_t)row * KTOT + k0 + koff);
    }
    __syncthreads();

    bf16x8 af[2], bfr[4];
#pragma unroll
    for (int i = 0; i < 2; ++i)
      af[i] = *(const bf16x8*)&As[i * 16 + cl][ksl];
#pragma unroll
    for (int j = 0; j < 4; ++j)
      bfr[j] = *(const bf16x8*)&Bs[wid * 64 + j * 16 + cl][ksl];
#pragma unroll
    for (int i = 0; i < 2; ++i)
#pragma unroll
      for (int j = 0; j < 4; ++j)
        acc[i][j] = __builtin_amdgcn_mfma_f32_16x16x32_bf16(af[i], bfr[j], acc[i][j], 0, 0, 0);
    __syncthreads();
  }

  int rb = (l >> 4) * 4;

  // ---- fused attention-dot epilogue ----
  if (DMODE == 1) {
    // wave wid == head wid (64 cols): plain stores
    float wdv[4], wsv[4];
#pragma unroll
    for (int j = 0; j < 4; ++j) {
      wdv[j] = attv[wid * 128 + j * 16 + cl];
      wsv[j] = attv[wid * 128 + 64 + j * 16 + cl];
    }
#pragma unroll
    for (int i = 0; i < 2; ++i)
#pragma unroll
      for (int r = 0; r < 4; ++r) {
        float pd = acc[i][0][r] * wdv[0] + acc[i][1][r] * wdv[1]
                 + acc[i][2][r] * wdv[2] + acc[i][3][r] * wdv[3];
        float ps = acc[i][0][r] * wsv[0] + acc[i][1][r] * wsv[1]
                 + acc[i][2][r] * wsv[2] + acc[i][3][r] * wsv[3];
#pragma unroll
        for (int d = 1; d < 16; d <<= 1) {
          pd += __shfl_xor(pd, d); ps += __shfl_xor(ps, d);
        }
        if (cl == 0) {
          int m = m0 + i * 16 + rb + r;
          if (m < M) {
            dotd[m * 4 + wid] = pd;
            dotsrc[m * 4 + wid] = ps;
          }
        }
      }
  } else if (DMODE == 2) {
    // slot sl spans 2 waves (128 cols); combine partials via LDS
    int sl = wid >> 1;
    int base = (wid & 1) * 64;
    float wdv[4], wsv[4];
#pragma unroll
    for (int j = 0; j < 4; ++j) {
      wdv[j] = attv[sl * 256 + base + j * 16 + cl];
      wsv[j] = attv[sl * 256 + 128 + base + j * 16 + cl];
    }
#pragma unroll
    for (int i = 0; i < 2; ++i)
#pragma unroll
      for (int r = 0; r < 4; ++r) {
        float pd = acc[i][0][r] * wdv[0] + acc[i][1][r] * wdv[1]
                 + acc[i][2][r] * wdv[2] + acc[i][3][r] * wdv[3];
        float ps = acc[i][0][r] * wsv[0] + acc[i][1][r] * wsv[1]
                 + acc[i][2][r] * wsv[2] + acc[i][3][r] * wsv[3];
#pragma unroll
        for (int d = 1; d < 16; d <<= 1) {
          pd += __shfl_xor(pd, d); ps += __shfl_xor(ps, d);
        }
        if (cl == 0) {
          int ml = i * 16 + rb + r;
          red[wid][ml][0] = pd;
          red[wid][ml][1] = ps;
        }
      }
    __syncthreads();
    if (t < 128) {
      int ml = t & 31, which = (t >> 5) & 1, sl2 = t >> 6;
      float v = red[sl2 * 2][ml][which] + red[sl2 * 2 + 1][ml][which];
      int m = m0 + ml;
      if (m < M) dotd[m * 4 + sl2 * 2 + which] = v;
    }
  }

#pragma unroll
  for (int i = 0; i < 2; ++i)
#pragma unroll
    for (int j = 0; j < 4; ++j)
#pragma unroll
      for (int r = 0; r < 4; ++r) {
        int m = m0 + i * 16 + rb + r;
        if (m < M)
          out[(size_t)m * 256 + wid * 64 + j * 16 + cl] = f2bf(acc[i][j][r]);
      }
}

// -------- layer-1 fused: ONE WAVE PER NODE, online softmax, bf16 out ------
// Gather unrolled x2: 4 uint4 loads in flight per wave (2 subgroups x 2).
__global__ __launch_bounds__(256) void fused_agg1_wave(
    const int* __restrict__ row_ptr, const int2* __restrict__ csr,
    const float* __restrict__ ad, const float* __restrict__ as_,
    const ushort* __restrict__ xp, const float* __restrict__ b1,
    ushort* __restrict__ hout, int N) {
  int n = blockIdx.x * 4 + (threadIdx.x >> 6);
  if (n >= N) return;
  int lane = threadIdx.x & 63;
  int h = lane & 3;
  int es = lane >> 2;
  int sg = lane >> 5, l = lane & 31, hl = l >> 3;

  int lo = row_ptr[n], hi = row_ptr[n + 1];
  float adv = ad[n * 4 + h];

  float m = -1e30f;
  float dsum = 0.f;
  float acc[8];
#pragma unroll
  for (int j = 0; j < 8; ++j) acc[j] = 0.f;

  for (int cb = lo; cb < hi; cb += 16) {
    int cn = min(16, hi - cb);
    float a = -1e30f;
    int sreg = 0;
    float wreg = 0.f;
    if (es < cn) {
      int2 sw = csr[cb + es];
      sreg = sw.x;
      wreg = __int_as_float(sw.y);
      float aa = adv + as_[sreg * 4 + h];
      a = aa >= 0.f ? aa : NEG_SLOPE * aa;
    }
    float cm = a;
    cm = fmaxf(cm, __shfl_xor(cm, 4));
    cm = fmaxf(cm, __shfl_xor(cm, 8));
    cm = fmaxf(cm, __shfl_xor(cm, 16));
    cm = fmaxf(cm, __shfl_xor(cm, 32));
    float mnew = fmaxf(m, cm);
    float scale = expf(m - mnew);       // first chunk: exp(-inf)=0
    m = mnew;
    float ev = (es < cn) ? expf(a - m) : 0.f;
    dsum = dsum * scale + ev;
    float cwreg = ev * wreg;
    float sc = __shfl(scale, hl);       // lane hl: (es=0, h=hl)
#pragma unroll
    for (int j = 0; j < 8; ++j) acc[j] *= sc;
    for (int el2 = 0; el2 < cn; el2 += 4) {
      int ea = el2 + sg, eb = el2 + 2 + sg;
      int eac = min(ea, cn - 1), ebc = min(eb, cn - 1);
      float cwa = __shfl(cwreg, (eac << 2) | hl);
      int sa = __shfl(sreg, eac << 2);
      float cwb = __shfl(cwreg, (ebc << 2) | hl);
      int sb = __shfl(sreg, ebc << 2);
      bool pa = ea < cn, pb = eb < cn;
      uint4 va, vb;
      if (pa) va = *(const uint4*)(xp + (size_t)sa * 256 + l * 8);
      if (pb) vb = *(const uint4*)(xp + (size_t)sb * 256 + l * 8);
      if (pa) {
        acc[0] += cwa * blo(va.x); acc[1] += cwa * bhi(va.x);
        acc[2] += cwa * blo(va.y); acc[3] += cwa * bhi(va.y);
        acc[4] += cwa * blo(va.z); acc[5] += cwa * bhi(va.z);
        acc[6] += cwa * blo(va.w); acc[7] += cwa * bhi(va.w);
      }
      if (pb) {
        acc[0] += cwb * blo(vb.x); acc[1] += cwb * bhi(vb.x);
        acc[2] += cwb * blo(vb.y); acc[3] += cwb * bhi(vb.y);
        acc[4] += cwb * blo(vb.z); acc[5] += cwb * bhi(vb.z);
        acc[6] += cwb * blo(vb.w); acc[7] += cwb * bhi(vb.w);
      }
    }
  }

  dsum += __shfl_xor(dsum, 4);
  dsum += __shfl_xor(dsum, 8);
  dsum += __shfl_xor(dsum, 16);
  dsum += __shfl_xor(dsum, 32);
  float den = __shfl(dsum, hl);

#pragma unroll
  for (int j = 0; j < 8; ++j) acc[j] += __shfl_down(acc[j], 32);

  if (sg == 0) {
    float inv = 1.0f / (den + SEPS);
    uint4 pk;
    uint32_t w[4];
#pragma unroll
    for (int q = 0; q < 4; ++q) {
      float v0 = acc[q * 2] * inv + b1[l * 8 + q * 2];
      float v1 = acc[q * 2 + 1] * inv + b1[l * 8 + q * 2 + 1];
      v0 = v0 > 0.f ? v0 : expm1f(v0);
      v1 = v1 > 0.f ? v1 : expm1f(v1);
      w[q] = (uint32_t)f2bf(v0) | ((uint32_t)f2bf(v1) << 16);
    }
    pk.x = w[0]; pk.y = w[1]; pk.z = w[2]; pk.w = w[3];
    *(uint4*)(hout + (size_t)n * 256 + l * 8) = pk;
  }
}

// -------- layer-2 fused: ONE WAVE PER NODE, online softmax, 16B gathers ---
__global__ __launch_bounds__(256) void fused_agg2_wave(
    const int* __restrict__ row_ptr, const int2* __restrict__ csr,
    const float* __restrict__ a4, const ushort* __restrict__ hp2,
    const float* __restrict__ bmu, const float* __restrict__ blv,
    float* __restrict__ out, int N) {
  int n = blockIdx.x * 4 + (threadIdx.x >> 6);
  if (n >= N) return;
  int lane = threadIdx.x & 63;
  int e31 = lane & 31;            // edge slot (alpha phase)
  int half = lane >> 5;           // alpha slot: 0=mu, 1=lv
  int sg = lane >> 5;             // gather subgroup
  int l = lane & 31;              // gather lane within subgroup
  int hh = l >> 4;                // row half this lane gathers (0=mu,1=lv)
  int hlane = hh << 5;            // representative lane of half hh

  int lo = row_ptr[n], hi = row_ptr[n + 1];
  float adv = a4[n * 4 + half * 2];

  float m = -1e30f;
  float dsum = 0.f;
  float acc[8];
#pragma unroll
  for (int j = 0; j < 8; ++j) acc[j] = 0.f;

  for (int cb = lo; cb < hi; cb += 32) {
    int cn = min(32, hi - cb);
    float a = -1e30f;
    int sreg = 0;
    float wreg = 0.f;
    if (e31 < cn) {
      int2 sw = csr[cb + e31];
      sreg = sw.x;
      wreg = __int_as_float(sw.y);
      float aa = adv + a4[sreg * 4 + half * 2 + 1];
      a = aa >= 0.f ? aa : NEG_SLOPE * aa;
    }
    // per-half chunk max (masks 1..16 stay within each 32-lane half)
    float cm = a;
    cm = fmaxf(cm, __shfl_xor(cm, 1));
    cm = fmaxf(cm, __shfl_xor(cm, 2));
    cm = fmaxf(cm, __shfl_xor(cm, 4));
    cm = fmaxf(cm, __shfl_xor(cm, 8));
    cm = fmaxf(cm, __shfl_xor(cm, 16));
    float mnew = fmaxf(m, cm);
    float scale = expf(m - mnew);       // first chunk: exp(-inf)=0
    m = mnew;
    float ev = (e31 < cn) ? expf(a - m) : 0.f;
    dsum = dsum * scale + ev;
    float cwreg = ev * wreg;
    float sc = __shfl(scale, hlane);    // my GATHER half's rescale
#pragma unroll
    for (int j = 0; j < 8; ++j) acc[j] *= sc;
    for (int el2 = 0; el2 < cn; el2 += 2) {
      int el = el2 + sg;
      int elc = min(el, cn - 1);
      float cw = __shfl(cwreg, elc | (hh << 5));   // half hh's weight, edge elc
      int s = __shfl(sreg, elc);                   // lanes 0-31 hold src ids
      if (el < cn) {
        uint4 v = *(const uint4*)(hp2 + (size_t)s * 256 + l * 8);
        acc[0] += cw * blo(v.x); acc[1] += cw * bhi(v.x);
        acc[2] += cw * blo(v.y); acc[3] += cw * bhi(v.y);
        acc[4] += cw * blo(v.z); acc[5] += cw * bhi(v.z);
        acc[6] += cw * blo(v.w); acc[7] += cw * bhi(v.w);
      }
    }
  }

  // per-half denom reduce
  dsum += __shfl_xor(dsum, 1);
  dsum += __shfl_xor(dsum, 2);
  dsum += __shfl_xor(dsum, 4);
  dsum += __shfl_xor(dsum, 8);
  dsum += __shfl_xor(dsum, 16);
  float den = __shfl(dsum, hlane);      // my gather half's denominator

  // cross-subgroup accumulate reduce (lane l and l+32 cover same channels)
#pragma unroll
  for (int j = 0; j < 8; ++j) acc[j] += __shfl_down(acc[j], 32);

  if (sg == 0) {
    float inv = 1.0f / (den + SEPS);
    const float* bb = hh ? blv : bmu;
    int c0 = (l & 15) * 8;
    float* op = out + (size_t)hh * N * 128 + (size_t)n * 128 + c0;
#pragma unroll
    for (int j = 0; j < 8; ++j) op[j] = acc[j] * inv + bb[c0 + j];
  }
}

extern "C" void kernel_launch(void* const* d_in, const int* in_sizes, int n_in,
                              void* d_out, int out_size, void* d_ws, size_t ws_size,
                              hipStream_t stream) {
  int OB = (out_size + 255) / 256;
  bool ok = (n_in == 12);
  int HID = 0, IN = 0, N = 0, LAT = 0, E = 0;
  if (ok) {
    HID = in_sizes[5];
    ok = ok && HID == 256;
    IN = HID ? in_sizes[3] / HID : 0;
    ok = ok && IN == 512 && in_sizes[3] == IN * HID;
    N = IN ? in_sizes[0] / IN : 0;
    ok = ok && N > 0 && in_sizes[0] == N * IN && (N % 4) == 0;
    LAT = in_sizes[8];
    ok = ok && LAT == 128;
    E = in_sizes[2];
    ok = ok && E > 0 && in_sizes[1] == 2 * E;
    ok = ok && in_sizes[4] == 2 * HID && in_sizes[6] == HID * LAT &&
         in_sizes[7] == 2 * LAT && in_sizes[9] == HID * LAT &&
         in_sizes[10] == 2 * LAT && in_sizes[11] == LAT &&
         out_size == 2 * N * LAT;
  }
  if (!ok) { fill_out<<<OB, 256, 0, stream>>>((float*)d_out, out_size, 2.0f); return; }

  char* p = (char*)d_ws;
  auto alloc = [&](size_t bytes) -> char* {
    char* r = p;
    p += (bytes + 255) & ~((size_t)255);
    return r;
  };
  ushort* xp_bf = (ushort*)alloc((size_t)N * HID * 2);   // later: hp2 (mu|lv)
  ushort* hreg  = (ushort*)alloc((size_t)N * HID * 2);   // bf16 h (post-ELU)
  ushort* WT1b  = (ushort*)alloc((size_t)HID * IN * 2);  // [256][512] bf16 transposed
  ushort* WallT = (ushort*)alloc((size_t)2 * LAT * HID * 2); // [256][256] bf16 (mu|lv)
  float*  dots  = (float*) alloc((size_t)N * 12 * 4);    // ad1 | as1 | a4
  float*  att1f = (float*) alloc((size_t)2 * HID * 4);
  float*  att2f = (float*) alloc((size_t)4 * LAT * 4);   // attmu(256) | attlv(256)
  float*  b1f   = (float*) alloc((size_t)HID * 4);
  float*  bmuf  = (float*) alloc((size_t)LAT * 4);
  float*  blvf  = (float*) alloc((size_t)LAT * 4);
  int2*   csr   = (int2*)  alloc((size_t)E * 8);         // {src, w} per slot
  int*    row_ptr=(int*)   alloc((size_t)(N + 1) * 4);
  int*    row_cur=(int*)   alloc((size_t)N * 4);
  int*    deg   = (int*)   alloc((size_t)N * 4);
  int*    modes = (int*)   alloc(16 * 4);

  size_t need = (size_t)(p - (char*)d_ws);
  if (need > ws_size) {
    fill_out<<<OB, 256, 0, stream>>>((float*)d_out, out_size, 3.0f);
    return;
  }

  ushort* hp2 = xp_bf;            // gemm2 writes after fused_agg1's last xp read
  float* ad1 = dots;
  float* as1 = dots + (size_t)N * 4;
  float* a4  = dots + (size_t)N * 8;

  // ---- prologue: detection + deg fill (single launch) ----
  const int fidx[11] = {0, 2, 3, 4, 5, 6, 7, 8, 9, 10, 11};
  DetPtrs dp;
  for (int i = 0; i < 11; ++i) {
    dp.p[i] = (const uint32_t*)d_in[fidx[i]];
    dp.n[i] = in_sizes[fidx[i]];
  }
  dp.idx = (const uint32_t*)d_in[1];
  dp.idxn = 2 * E;
  int nbDeg = (N + 255) / 256;
  prologue<<<12 + nbDeg, 256, 0, stream>>>(dp, modes, deg, N);

  // ---- canonicalization (single launch) ----
  int EB1 = (E + 255) / 256;
  int WB = (HID * IN + 2 * LAT * HID + 255) / 256;
  CanArgs ca;
  ca.ei = d_in[1];
  ca.deg = deg;
  ca.E = E; ca.N = N; ca.EB1 = EB1; ca.WB = WB;
  ca.wt.w1 = d_in[3]; ca.wt.wmu = d_in[6]; ca.wt.wlv = d_in[9];
  ca.wt.wt1 = WT1b; ca.wt.wall = WallT;
  ca.sc.src[0] = d_in[4];  ca.sc.dst[0] = att1f;        ca.sc.n[0] = 2 * HID; ca.sc.mi[0] = 3;
  ca.sc.src[1] = d_in[5];  ca.sc.dst[1] = b1f;          ca.sc.n[1] = HID;     ca.sc.mi[1] = 4;
  ca.sc.src[2] = d_in[7];  ca.sc.dst[2] = att2f;        ca.sc.n[2] = 2 * LAT; ca.sc.mi[2] = 6;
  ca.sc.src[3] = d_in[8];  ca.sc.dst[3] = bmuf;         ca.sc.n[3] = LAT;     ca.sc.mi[3] = 7;
  ca.sc.src[4] = d_in[10]; ca.sc.dst[4] = att2f + 256;  ca.sc.n[4] = 2 * LAT; ca.sc.mi[4] = 9;
  ca.sc.src[5] = d_in[11]; ca.sc.dst[5] = blvf;         ca.sc.n[5] = LAT;     ca.sc.mi[5] = 10;
  canon_all<<<EB1 + WB + 6, 256, 0, stream>>>(ca, modes);

  // ---- CSR scan ----
  scan_deg<<<1, 1024, 0, stream>>>(deg, row_ptr, row_cur, N);

  int MB = (N + 31) / 32;

  // ---- layer 1: scatter (blocks 0..EB1) + GEMM (blocks EB1..) in ONE launch
  gemm_mfma_sc<512, 1><<<EB1 + MB, 256, 0, stream>>>(
      d_in[0], WT1b, xp_bf, N, &modes[0], att1f, ad1, as1,
      EB1, d_in[1], d_in[2], row_cur, csr, E);
  fused_agg1_wave<<<(N + 3) / 4, 256, 0, stream>>>(row_ptr, csr,
                                                   ad1, as1, xp_bf, b1f, hreg, N);

  // ---- layer 2 (single GEMM mu|lv, bf16 A + fused node dots) ----
  gemm_mfma_sc<256, 2><<<MB, 256, 0, stream>>>(
      hreg, WallT, hp2, N, nullptr, att2f, a4, nullptr,
      0, nullptr, nullptr, nullptr, nullptr, 0);
  fused_agg2_wave<<<(N + 3) / 4, 256, 0, stream>>>(row_ptr, csr, a4,
                                                   hp2, bmuf, blvf,
                                                   (float*)d_out, N);
}